// Round 25
// baseline (18.786 us; speedup 1.0000x reference)
//
#include <hip/hip_runtime.h>
#include <math.h>

#define N_ROWS 1024
#define RANK   8
#define M_COLS 4096

#define R_ROWS   2      // n-rows per thread
#define T_PTS    2      // direct points per thread in [1,2048], stride 1024
#define M_STRIDE 1024

// Static device scratch (fully overwritten every call before read).
__device__ float2 g_Hft[RANK * M_COLS];    // full FFT of softplus(H), 256 KB
__device__ float4 g_Tab4[N_ROWS * RANK];   // {vr, vi, wcr, wci} per (n,d), 128 KB
__device__ float2 g_Tab2[N_ROWS * RANK];   // {ws, tau}          per (n,d),  64 KB

// fast softplus: 2 trans + ~4 VALU. exact for x>20; inputs are ~N(0,1).
__device__ __forceinline__ float softplus_f(float x) {
    float t = __expf(x);
    float r = 0.69314718056f * __log2f(1.0f + t);
    return (x > 20.0f) ? x : r;
}
// hw trig: v_sin/v_cos compute sin/cos(2*pi*x), x in revolutions.
__device__ __forceinline__ float sin_rev(float x) { return __builtin_amdgcn_sinf(x); }
__device__ __forceinline__ float cos_rev(float x) { return __builtin_amdgcn_cosf(x); }
__device__ __forceinline__ float fract_f(float x) { return __builtin_amdgcn_fractf(x); }

// ---------------------------------------------------------------------------
// fft, 4-way split (R24-proven, absmax 1.0): 256 blocks x 512 threads
// (ALL 256 CUs active). Block b: d = b>>5, m0b = (b&31)*2 + {0,1}.
// Stage A: quarter q sums 16 k1-terms; init twiddle is exactly i^{-(q*m0 mod 4)}.
// Stage B: quarter q sums 16 k0-terms (trig init); 4-way LDS combine; write.
// Blocks 0..15 fill Tab4/Tab2 (side-job, 8192 entries).
// ---------------------------------------------------------------------------
__global__ void fft_fused(const float* __restrict__ H,
                          const float* __restrict__ W,
                          const float* __restrict__ tau) {
    __shared__ float  sHs[M_COLS];        // 16 KB
    __shared__ float2 sY [2 * 64];        // stage-A combined, [m0j][k0], 1 KB
    __shared__ float2 sP [512];           // partials (A and B), 4 KB

    const int tid = threadIdx.x;          // 0..511
    const int b   = blockIdx.x;           // 0..255
    const int d   = b >> 5;
    const int m0b = (b & 31) << 1;

    if (b < 16) {                         // table side-job: 16 x 512 = 8192
        int t = b * 512 + tid;
        float w  = softplus_f(W[t]);
        float tv = tau[t];
        float rv = fract_f(tv * ((float)M_STRIDE / (float)M_COLS));  // tv/4
        float4 t4;
        t4.x = cos_rev(rv);               // step = e^{+i 2pi tau*1024/M}
        t4.y = sin_rev(rv);
        float rc = fract_f(-tv);          // e^{-2pi i tau}
        t4.z = w * cos_rev(rc);           // wcr
        t4.w = w * sin_rev(rc);           // wci
        g_Tab4[t] = t4;
        g_Tab2[t] = make_float2(w, tv);
    }

    const float4* Hrow4 = (const float4*)(H + d * M_COLS);
    #pragma unroll
    for (int p = 0; p < 2; ++p) {
        int i = p * 512 + tid;
        float4 h4 = Hrow4[i];
        sHs[i*4+0] = softplus_f(h4.x);
        sHs[i*4+1] = softplus_f(h4.y);
        sHs[i*4+2] = softplus_f(h4.z);
        sHs[i*4+3] = softplus_f(h4.w);
    }
    __syncthreads();

    {   // stage A partial: tid = q*128 + m0j*64 + k0 ; 16 k1-terms per thread
        int k0  = tid & 63;
        int m0j = (tid >> 6) & 1;
        int q   = tid >> 7;               // 0..3
        int m0  = m0b + m0j;
        float mrev = (float)m0 * (1.0f / 64.0f);
        float rr =  cos_rev(mrev);
        float ri = -sin_rev(mrev);        // rot = e^{-2pi i m0/64}
        int q4 = (q * m0) & 3;            // init tw = i^{-q4}, exact
        float twr = (q4 == 0) ? 1.0f : ((q4 == 2) ? -1.0f : 0.0f);
        float twi = (q4 == 1) ? -1.0f : ((q4 == 3) ? 1.0f : 0.0f);
        float ar = 0.0f, ai = 0.0f;
        int base = q << 4;                // k1 start
        #pragma unroll
        for (int k = 0; k < 16; ++k) {
            float v = sHs[((base + k) << 6) + k0];
            ar = fmaf(v, twr, ar);
            ai = fmaf(v, twi, ai);
            float nr = fmaf(twr, rr, -(twi * ri));
            twi      = fmaf(twr, ri,   twi * rr);
            twr = nr;
        }
        sP[tid] = make_float2(ar, ai);
    }
    __syncthreads();
    if (tid < 128) {                      // 4-way combine: sY[m0j*64+k0]
        float2 a = sP[tid],       c = sP[128 + tid];
        float2 e = sP[256 + tid], f = sP[384 + tid];
        sY[tid] = make_float2(a.x + c.x + e.x + f.x,
                              a.y + c.y + e.y + f.y);
    }
    __syncthreads();

    {   // stage B partial: tid = q*128 + m0j*64 + m1 ; 16 k0-terms per thread
        int m1  = tid & 63;
        int m0j = (tid >> 6) & 1;
        int q   = tid >> 7;
        int m   = (m1 << 6) + m0b + m0j;
        float mrev = (float)m * (1.0f / 4096.0f);
        float rr =  cos_rev(mrev);
        float ri = -sin_rev(mrev);        // rot = e^{-2pi i m/4096}
        float irev = (float)((m * (q << 4)) & 4095) * (1.0f / 4096.0f);
        float twr =  cos_rev(irev);       // init tw = e^{-2pi i(16q m)/4096}
        float twi = -sin_rev(irev);
        float ar = 0.0f, ai = 0.0f;
        int base = q << 4;                // k0 start
        #pragma unroll
        for (int k = 0; k < 16; ++k) {
            float2 y = sY[(m0j << 6) + base + k];
            ar = fmaf(y.x, twr, fmaf(-y.y, twi, ar));
            ai = fmaf(y.x, twi, fmaf( y.y, twr, ai));
            float nr = fmaf(twr, rr, -(twi * ri));
            twi      = fmaf(twr, ri,   twi * rr);
            twr = nr;
        }
        sP[tid] = make_float2(ar, ai);
    }
    __syncthreads();
    if (tid < 128) {                      // combine + write
        int m1 = tid & 63, m0j = tid >> 6;
        float2 a = sP[tid],       c = sP[128 + tid];
        float2 e = sP[256 + tid], f = sP[384 + tid];
        int m = (m1 << 6) + m0b + m0j;
        g_Hft[d * M_COLS + m] = make_float2(a.x + c.x + e.x + f.x,
                                            a.y + c.y + e.y + f.y);
    }
}

// ---------------------------------------------------------------------------
// Main: R22 VERBATIM (18.56us-proven): 256-thread blocks, grid (4,512) =
// 2048 blocks = 8 waves/SIMD, launch_bounds(256,8) 64-VGPR cap (spill-free
// for this ~45-reg live set), no fract (hw sin/cos domain covers |x|<~3).
// For m = 1+m0+j*1024:  u = e^{+i 2pi tau m/M}
//   zr = ur*hr + ui*hi ; zi = ur*hi - ui*hr
//   Re V[n,m]      += ws * zr
//   Re V[n,4096-m] += wcr*zr + wci*zi      (Hermitian mirror)
// ---------------------------------------------------------------------------
__global__ __launch_bounds__(256, 8)
void shiftnmf_main(float* __restrict__ out) {
    int tid = threadIdx.x;
    int m0  = blockIdx.x * 256 + tid;     // 0..1023 ; m_j = 1 + m0 + j*1024
    int n0  = blockIdx.y * R_ROWS;

    float fm0 = (float)(1 + m0) * (1.0f / (float)M_COLS);

    float accm[R_ROWS][T_PTS];            // direct outputs, m
    float accx[R_ROWS][T_PTS];            // mirror outputs, 4096-m
    #pragma unroll
    for (int r = 0; r < R_ROWS; ++r)
        #pragma unroll
        for (int j = 0; j < T_PTS; ++j) { accm[r][j] = 0.0f; accx[r][j] = 0.0f; }

    #pragma unroll
    for (int d = 0; d < RANK; ++d) {
        float ur[R_ROWS], ui[R_ROWS];                 // unit phasor (per-lane)
        float vr[R_ROWS], vi[R_ROWS];                 // step (uniform)
        float ws[R_ROWS], wcr[R_ROWS], wci[R_ROWS];   // weights (uniform)
        #pragma unroll
        for (int r = 0; r < R_ROWS; ++r) {
            int nd = (n0 + r) * RANK + d;
            float4 t4 = g_Tab4[nd];                   // block-uniform
            float2 t2 = g_Tab2[nd];
            vr[r]  = t4.x;  vi[r]  = t4.y;
            wcr[r] = t4.z;  wci[r] = t4.w;
            ws[r]  = t2.x;
            float r0 = t2.y * fm0;                    // |r0| < ~3: hw domain ok
            ur[r] = cos_rev(r0);                      // u = e^{+i 2pi tau m_0/M}
            ui[r] = sin_rev(r0);
        }

        const float2* hp = g_Hft + d * M_COLS + 1 + m0;
        #pragma unroll
        for (int j = 0; j < T_PTS; ++j) {
            float2 h = hp[j * M_STRIDE];              // coalesced, L2-resident
            #pragma unroll
            for (int r = 0; r < R_ROWS; ++r) {
                float t1v = ui[r] * h.y;
                float zr = fmaf(ur[r], h.x, t1v);     // Re(conj(u)h)
                float t2v = ui[r] * h.x;
                float zi = fmaf(ur[r], h.y, -t2v);    // Im(conj(u)h)
                accm[r][j] = fmaf(ws[r],  zr, accm[r][j]);
                accx[r][j] = fmaf(wcr[r], zr, fmaf(wci[r], zi, accx[r][j]));
                if (j < T_PTS - 1) {                  // u *= v (skip dead last)
                    float nr = fmaf(ur[r], vr[r], -(ui[r] * vi[r]));
                    ui[r]    = fmaf(ur[r], vi[r],   ui[r] * vr[r]);
                    ur[r]    = nr;
                }
            }
        }
    }

    #pragma unroll
    for (int r = 0; r < R_ROWS; ++r) {
        float* op = out + (n0 + r) * M_COLS;
        #pragma unroll
        for (int j = 0; j < T_PTS; ++j)
            op[1 + m0 + j * M_STRIDE] = accm[r][j];    // m in [1,2048]
        #pragma unroll
        for (int j = 0; j < T_PTS; ++j)
            op[4095 - m0 - j * M_STRIDE] = accx[r][j]; // 4096-m in [2048,4095]
    }

    if (blockIdx.x == 0 && tid == 0) {                // column 0, direct
        #pragma unroll
        for (int r = 0; r < R_ROWS; ++r) {
            int n = n0 + r;
            float a = 0.0f;
            #pragma unroll
            for (int d = 0; d < RANK; ++d)
                a = fmaf(g_Tab2[n * RANK + d].x, g_Hft[d * M_COLS].x, a);
            out[n * M_COLS] = a;
        }
    }
}

extern "C" void kernel_launch(void* const* d_in, const int* in_sizes, int n_in,
                              void* d_out, int out_size, void* d_ws, size_t ws_size,
                              hipStream_t stream) {
    const float* W   = (const float*)d_in[0];   // [1024, 8]
    const float* H   = (const float*)d_in[1];   // [8, 4096]
    const float* tau = (const float*)d_in[2];   // [1024, 8]

    fft_fused<<<dim3(256), dim3(512), 0, stream>>>(H, W, tau);

    dim3 grid(M_COLS / 2 / (256 * T_PTS), N_ROWS / R_ROWS);  // (4, 512)
    shiftnmf_main<<<grid, dim3(256), 0, stream>>>((float*)d_out);
}

// Round 26
// 18.050 us; speedup vs baseline: 1.0407x; 1.0407x over previous
//
#include <hip/hip_runtime.h>
#include <math.h>

#define N_ROWS 1024
#define RANK   8
#define M_COLS 4096

#define R_ROWS   2      // n-rows per thread
#define T_PTS    2      // direct points per thread in [1,2048], stride 1024
#define M_STRIDE 1024

// Static device scratch (fully overwritten every call before read).
__device__ float2 g_Hft[RANK * M_COLS];    // full FFT of softplus(H), 256 KB
__device__ float4 g_Tab4[N_ROWS * RANK];   // {vr, vi, wcr, wci} per (n,d), 128 KB
__device__ float2 g_Tab2[N_ROWS * RANK];   // {ws, tau}          per (n,d),  64 KB

// fast softplus: 2 trans + ~4 VALU. exact for x>20; inputs are ~N(0,1).
__device__ __forceinline__ float softplus_f(float x) {
    float t = __expf(x);
    float r = 0.69314718056f * __log2f(1.0f + t);
    return (x > 20.0f) ? x : r;
}
// hw trig: v_sin/v_cos compute sin/cos(2*pi*x), x in revolutions.
__device__ __forceinline__ float sin_rev(float x) { return __builtin_amdgcn_sinf(x); }
__device__ __forceinline__ float cos_rev(float x) { return __builtin_amdgcn_cosf(x); }
__device__ __forceinline__ float fract_f(float x) { return __builtin_amdgcn_fractf(x); }

// ---------------------------------------------------------------------------
// Widened fused FFT (R18/R22-proven, verbatim): 128 blocks x 512 threads,
// split-sum stages, blocks 0..15 fill Tab4/Tab2.
// ---------------------------------------------------------------------------
__global__ void fft_fused(const float* __restrict__ H,
                          const float* __restrict__ W,
                          const float* __restrict__ tau) {
    __shared__ float  sHs[M_COLS];        // 16 KB
    __shared__ float2 sY [4 * 64];        // stage-A combined, [m0j][k0], 2 KB
    __shared__ float2 sP [512];           // partials (A and B), 4 KB

    const int tid = threadIdx.x;          // 0..511
    const int b   = blockIdx.x;           // 0..127
    const int d   = b >> 4;
    const int m0b = (b & 15) << 2;

    if (b < 16) {                         // table side-job: 16 x 512 = 8192
        int t = b * 512 + tid;
        float w  = softplus_f(W[t]);
        float tv = tau[t];
        float rv = fract_f(tv * ((float)M_STRIDE / (float)M_COLS));  // tv/4
        float4 t4;
        t4.x = cos_rev(rv);               // step = e^{+i 2pi tau*1024/M}
        t4.y = sin_rev(rv);
        float rc = fract_f(-tv);          // e^{-2pi i tau}
        t4.z = w * cos_rev(rc);           // wcr
        t4.w = w * sin_rev(rc);           // wci
        g_Tab4[t] = t4;
        g_Tab2[t] = make_float2(w, tv);
    }

    const float4* Hrow4 = (const float4*)(H + d * M_COLS);
    #pragma unroll
    for (int p = 0; p < 2; ++p) {
        int i = p * 512 + tid;
        float4 h4 = Hrow4[i];
        sHs[i*4+0] = softplus_f(h4.x);
        sHs[i*4+1] = softplus_f(h4.y);
        sHs[i*4+2] = softplus_f(h4.z);
        sHs[i*4+3] = softplus_f(h4.w);
    }
    __syncthreads();

    {   // stage A partial: tid = half*256 + m0j*64 + k0
        int k0   = tid & 63;
        int m0j  = (tid >> 6) & 3;
        int half = tid >> 8;
        int m0   = m0b + m0j;
        float mrev = (float)m0 * (1.0f / 64.0f);
        float rr =  cos_rev(mrev);
        float ri = -sin_rev(mrev);        // rot = e^{-2pi i m0/64}
        float twr = ((half & m0) & 1) ? -1.0f : 1.0f;   // exact init
        float twi = 0.0f;
        float ar = 0.0f, ai = 0.0f;
        int base = half << 5;
        #pragma unroll
        for (int k = 0; k < 32; ++k) {
            float v = sHs[((base + k) << 6) + k0];
            ar = fmaf(v, twr, ar);
            ai = fmaf(v, twi, ai);
            float nr = fmaf(twr, rr, -(twi * ri));
            twi      = fmaf(twr, ri,   twi * rr);
            twr = nr;
        }
        sP[tid] = make_float2(ar, ai);
    }
    __syncthreads();
    if (tid < 256) {
        float2 a = sP[tid], c = sP[256 + tid];
        sY[tid] = make_float2(a.x + c.x, a.y + c.y);
    }
    __syncthreads();

    {   // stage B partial: tid = half*256 + m0j*64 + m1
        int m1   = tid & 63;
        int m0j  = (tid >> 6) & 3;
        int half = tid >> 8;
        int m    = (m1 << 6) + m0b + m0j;
        float mrev = (float)m * (1.0f / 4096.0f);
        float rr =  cos_rev(mrev);
        float ri = -sin_rev(mrev);        // rot = e^{-2pi i m/4096}
        float irev = (float)((m * (half << 5)) & 4095) * (1.0f / 4096.0f);
        float twr =  cos_rev(irev);
        float twi = -sin_rev(irev);
        float ar = 0.0f, ai = 0.0f;
        int base = half << 5;
        #pragma unroll
        for (int k = 0; k < 32; ++k) {
            float2 y = sY[(m0j << 6) + base + k];
            ar = fmaf(y.x, twr, fmaf(-y.y, twi, ar));
            ai = fmaf(y.x, twi, fmaf( y.y, twr, ai));
            float nr = fmaf(twr, rr, -(twi * ri));
            twi      = fmaf(twr, ri,   twi * rr);
            twr = nr;
        }
        sP[tid] = make_float2(ar, ai);
    }
    __syncthreads();
    if (tid < 256) {
        int m1 = tid & 63, m0j = tid >> 6;
        float2 a = sP[tid], c = sP[256 + tid];
        int m = (m1 << 6) + m0b + m0j;
        g_Hft[d * M_COLS + m] = make_float2(a.x + c.x, a.y + c.y);
    }
}

// ---------------------------------------------------------------------------
// Main: R22 VERBATIM except all output stores are NONTEMPORAL (output is
// write-once-never-read; bypassing L2 keeps the 256KB g_Hft working set
// resident per-XCD instead of being evicted by 2MB/XCD of write traffic).
// For m = 1+m0+j*1024:  u = e^{+i 2pi tau m/M}
//   zr = ur*hr + ui*hi ; zi = ur*hi - ui*hr
//   Re V[n,m]      += ws * zr
//   Re V[n,4096-m] += wcr*zr + wci*zi      (Hermitian mirror)
// grid (4,512) = 2048 blocks = 8 waves/SIMD; launch_bounds(256,8).
// ---------------------------------------------------------------------------
__global__ __launch_bounds__(256, 8)
void shiftnmf_main(float* __restrict__ out) {
    int tid = threadIdx.x;
    int m0  = blockIdx.x * 256 + tid;     // 0..1023 ; m_j = 1 + m0 + j*1024
    int n0  = blockIdx.y * R_ROWS;

    float fm0 = (float)(1 + m0) * (1.0f / (float)M_COLS);

    float accm[R_ROWS][T_PTS];            // direct outputs, m
    float accx[R_ROWS][T_PTS];            // mirror outputs, 4096-m
    #pragma unroll
    for (int r = 0; r < R_ROWS; ++r)
        #pragma unroll
        for (int j = 0; j < T_PTS; ++j) { accm[r][j] = 0.0f; accx[r][j] = 0.0f; }

    #pragma unroll
    for (int d = 0; d < RANK; ++d) {
        float ur[R_ROWS], ui[R_ROWS];                 // unit phasor (per-lane)
        float vr[R_ROWS], vi[R_ROWS];                 // step (uniform)
        float ws[R_ROWS], wcr[R_ROWS], wci[R_ROWS];   // weights (uniform)
        #pragma unroll
        for (int r = 0; r < R_ROWS; ++r) {
            int nd = (n0 + r) * RANK + d;
            float4 t4 = g_Tab4[nd];                   // block-uniform
            float2 t2 = g_Tab2[nd];
            vr[r]  = t4.x;  vi[r]  = t4.y;
            wcr[r] = t4.z;  wci[r] = t4.w;
            ws[r]  = t2.x;
            float r0 = t2.y * fm0;                    // |r0| < ~3: hw domain ok
            ur[r] = cos_rev(r0);                      // u = e^{+i 2pi tau m_0/M}
            ui[r] = sin_rev(r0);
        }

        const float2* hp = g_Hft + d * M_COLS + 1 + m0;
        #pragma unroll
        for (int j = 0; j < T_PTS; ++j) {
            float2 h = hp[j * M_STRIDE];              // coalesced, L2-resident
            #pragma unroll
            for (int r = 0; r < R_ROWS; ++r) {
                float t1v = ui[r] * h.y;
                float zr = fmaf(ur[r], h.x, t1v);     // Re(conj(u)h)
                float t2v = ui[r] * h.x;
                float zi = fmaf(ur[r], h.y, -t2v);    // Im(conj(u)h)
                accm[r][j] = fmaf(ws[r],  zr, accm[r][j]);
                accx[r][j] = fmaf(wcr[r], zr, fmaf(wci[r], zi, accx[r][j]));
                if (j < T_PTS - 1) {                  // u *= v (skip dead last)
                    float nr = fmaf(ur[r], vr[r], -(ui[r] * vi[r]));
                    ui[r]    = fmaf(ur[r], vi[r],   ui[r] * vr[r]);
                    ur[r]    = nr;
                }
            }
        }
    }

    #pragma unroll
    for (int r = 0; r < R_ROWS; ++r) {
        float* op = out + (n0 + r) * M_COLS;
        #pragma unroll
        for (int j = 0; j < T_PTS; ++j)
            __builtin_nontemporal_store(accm[r][j], op + 1 + m0 + j * M_STRIDE);
        #pragma unroll
        for (int j = 0; j < T_PTS; ++j)
            __builtin_nontemporal_store(accx[r][j], op + 4095 - m0 - j * M_STRIDE);
    }

    if (blockIdx.x == 0 && tid == 0) {                // column 0, direct
        #pragma unroll
        for (int r = 0; r < R_ROWS; ++r) {
            int n = n0 + r;
            float a = 0.0f;
            #pragma unroll
            for (int d = 0; d < RANK; ++d)
                a = fmaf(g_Tab2[n * RANK + d].x, g_Hft[d * M_COLS].x, a);
            __builtin_nontemporal_store(a, out + n * M_COLS);
        }
    }
}

extern "C" void kernel_launch(void* const* d_in, const int* in_sizes, int n_in,
                              void* d_out, int out_size, void* d_ws, size_t ws_size,
                              hipStream_t stream) {
    const float* W   = (const float*)d_in[0];   // [1024, 8]
    const float* H   = (const float*)d_in[1];   // [8, 4096]
    const float* tau = (const float*)d_in[2];   // [1024, 8]

    fft_fused<<<dim3(128), dim3(512), 0, stream>>>(H, W, tau);

    dim3 grid(M_COLS / 2 / (256 * T_PTS), N_ROWS / R_ROWS);  // (4, 512)
    shiftnmf_main<<<grid, dim3(256), 0, stream>>>((float*)d_out);
}